// Round 15
// baseline (276.117 us; speedup 1.0000x reference)
//
#include <hip/hip_runtime.h>
#include <hip/hip_bf16.h>

#define N_NODE  50000
#define N_PAD   50048   // 391 * 128  (exactly tiled by 128 -> no guards)
#define N_GRAPH 1024
#define DD      512
#define NK8     8       // fp8 cores: 64-byte K-step, K=512 -> 8 steps
#define NJSD    3128    // jsd grid: 391 * 8

typedef __attribute__((ext_vector_type(4))) float f32x4;
typedef __attribute__((ext_vector_type(2))) long long ll2;

// fp32 -> fp8 e4m3fn, RNE, BRANCHLESS (R8 lesson: early-returns diverge)
__device__ __forceinline__ unsigned char f2fp8(float f) {
  unsigned int u = __builtin_bit_cast(unsigned int, f);
  unsigned int sg = (u >> 24) & 0x80u;
  float a = __builtin_bit_cast(float, u & 0x7fffffffu);
  a = fminf(a, 448.0f);
  unsigned int r = __builtin_bit_cast(unsigned int, a);
  unsigned int rn = r + 0x7ffffu + ((r >> 20) & 1u);   // RNE at mantissa bit 20
  int codeN = (int)(rn >> 20) - (120 << 3);            // ((e+127)<<3|m3) - 960
  int codeS = (int)rintf(a * 512.0f);                  // subnormal grid 2^-9
  int code = (a >= 0.015625f) ? codeN : codeS;
  code = code > 0x7E ? 0x7E : code;
  return (unsigned char)(sg | (unsigned int)code);
}

// K-permutation (R10-verified): within each 64-col group, phys position
// p = ((k>>3)&3)<<4 | (k>>5)<<3 | (k&7). A lane's two MFMA kk-operands are
// then 16 contiguous bytes (one b128 read). Upper bits pass through.
__device__ __forceinline__ long long permute_col(long long c) {
  int o = (int)c & 63;
  int p = (((o >> 3) & 3) << 4) | ((o >> 5) << 3) | (o & 7);
  return (c & ~63LL) | p;
}

__device__ __forceinline__ void gload16(const void* g, void* l) {
  __builtin_amdgcn_global_load_lds(
      (const __attribute__((address_space(1))) unsigned int*)g,
      (__attribute__((address_space(3))) unsigned int*)l, 16, 0, 0);
}

// direct global->reg b128 load, manually counted (volatile keeps issue order)
__device__ __forceinline__ ll2 gldB(const unsigned char* p) {
  ll2 r;
  asm volatile("global_load_dwordx4 %0, %1, off" : "=v"(r) : "v"(p));
  return r;
}

// T1: bijective XCD-chunk remap (m204 variant)
__device__ __forceinline__ int xcd_remap(int bid, int nwg) {
  int xcd = bid & 7;
  int local = bid >> 3;
  int q = nwg >> 3, r = nwg & 7;
  int base = (xcd < r) ? xcd * (q + 1) : r * (q + 1) + (xcd - r) * q;
  return base + local;
}

// ---- fp8 cast kernels (write K-permuted) ------------------------------------

__global__ void cast_pad8_kernel(const float* __restrict__ src,
                                 unsigned char* __restrict__ dst,
                                 int srcRows, int dstRows) {
  long long base = ((long long)blockIdx.x * blockDim.x + threadIdx.x) * 8;
  if (base >= (long long)dstRows * DD) return;
  int row = (int)(base >> 9);
  unsigned long long pk = 0ULL;
  if (row < srcRows) {
    float4 x0 = reinterpret_cast<const float4*>(src + base)[0];
    float4 x1 = reinterpret_cast<const float4*>(src + base)[1];
    pk  = (unsigned long long)f2fp8(x0.x);
    pk |= (unsigned long long)f2fp8(x0.y) << 8;
    pk |= (unsigned long long)f2fp8(x0.z) << 16;
    pk |= (unsigned long long)f2fp8(x0.w) << 24;
    pk |= (unsigned long long)f2fp8(x1.x) << 32;
    pk |= (unsigned long long)f2fp8(x1.y) << 40;
    pk |= (unsigned long long)f2fp8(x1.z) << 48;
    pk |= (unsigned long long)f2fp8(x1.w) << 56;
  }
  *reinterpret_cast<unsigned long long*>(dst + permute_col(base)) = pk;
}

struct WPtrs { const float* p[8]; };

__global__ void cast_w8_kernel(WPtrs ps, unsigned char* __restrict__ dst) {
  long long base = ((long long)blockIdx.x * blockDim.x + threadIdx.x) * 8;
  int mat = (int)(base >> 18);           // 512*512 = 2^18 elems per matrix
  long long off = base & 262143LL;
  const float* s = ps.p[mat] + off;
  float4 x0 = reinterpret_cast<const float4*>(s)[0];
  float4 x1 = reinterpret_cast<const float4*>(s)[1];
  unsigned long long pk;
  pk  = (unsigned long long)f2fp8(x0.x);
  pk |= (unsigned long long)f2fp8(x0.y) << 8;
  pk |= (unsigned long long)f2fp8(x0.z) << 16;
  pk |= (unsigned long long)f2fp8(x0.w) << 24;
  pk |= (unsigned long long)f2fp8(x1.x) << 32;
  pk |= (unsigned long long)f2fp8(x1.y) << 40;
  pk |= (unsigned long long)f2fp8(x1.z) << 48;
  pk |= (unsigned long long)f2fp8(x1.w) << 56;
  *reinterpret_cast<unsigned long long*>(
      dst + (long long)mat * 262144 + permute_col(off)) = pk;
}

__global__ void zeropad8_kernel(unsigned char* __restrict__ H) {
  long long i = (long long)blockIdx.x * blockDim.x + threadIdx.x;
  long long base = (long long)N_NODE * DD + i * 16;
  if (base < (long long)N_PAD * DD) {
    int4 z = {0, 0, 0, 0};
    *reinterpret_cast<int4*>(H + base) = z;
  }
}

// ============================================================================
// 128x128 fp8 core, B-DIRECT variant: A staged via 4-slot circular LDS with
// counted vmcnt (R10-R13 skeleton); B read straight from global (L2-hot:
// g_enc 512KB / W 256KB) into regs via counted inline-asm b128 loads.
// LDS = As only = 32 KB -> up to 4 blocks/CU.
// Per-step VMEM issue order (volatile asm + sched_barrier fences):
//   [b_t (4)] [st_{t+3} (2)]  -> wait vmcnt(2) retires b_t (st_{t+3} newer).
// st_t readiness for this step's ds_read: previous step's wait retired
// b_{t-1}, which is NEWER than st_t (issued step t-3) -> st_t landed; the
// step-start barrier makes that block-wide. Prologue: vmcnt(4) retires st0.
// WAR: st_{t+3} overwrites slot t-1, whose readers finished pre-barrier.
// ============================================================================

struct BP4 { const unsigned char* p[4]; };

__device__ __forceinline__ void stageA(const unsigned char* aptr, int kbyte,
                                       unsigned char* sA, int wid) {
  unsigned char* dA = sA + wid * 1024;   // wave-uniform; HW adds lane*16B
  gload16(aptr + kbyte, dA);
  gload16(aptr + 64LL * DD + kbyte, dA + 4096);
}

__device__ __forceinline__ void gemm_core128_bd(
    const unsigned char* aptr, const BP4& bp,
    unsigned char* As, int wid, int rA, int offsA, f32x4 acc[4][4]) {
  stageA(aptr, 0, As, wid);
  stageA(aptr, 64, As + 8192, wid);
  stageA(aptr, 128, As + 16384, wid);
  asm volatile("s_waitcnt vmcnt(4)" ::: "memory");   // st0 retired
  __builtin_amdgcn_sched_barrier(0);
  __builtin_amdgcn_s_barrier();
  #pragma unroll
  for (int t = 0; t < NK8; ++t) {
    if (t) __builtin_amdgcn_s_barrier();
    ll2 b[4];
    #pragma unroll
    for (int n = 0; n < 4; ++n) b[n] = gldB(bp.p[n] + t * 64);
    __builtin_amdgcn_sched_barrier(0);   // keep b-issue BEFORE stage-issue
    if (t + 3 < NK8)
      stageA(aptr, (t + 3) * 64, As + ((t + 3) & 3) * 8192, wid);
    __builtin_amdgcn_sched_barrier(0);
    const unsigned char* as = As + (t & 3) * 8192;
    ll2 a[4];
    #pragma unroll
    for (int m = 0; m < 4; ++m)
      a[m] = *reinterpret_cast<const ll2*>(as + (rA + m * 16) * 64 + offsA);
    if (t + 3 < NK8) asm volatile("s_waitcnt vmcnt(2)" ::: "memory");
    else             asm volatile("s_waitcnt vmcnt(0)" ::: "memory");
    __builtin_amdgcn_sched_barrier(0);   // rule 18: pin MFMA after the waits
    __builtin_amdgcn_s_setprio(1);
    #pragma unroll
    for (int m = 0; m < 4; ++m)
      #pragma unroll
      for (int n = 0; n < 4; ++n)
        acc[m][n] = __builtin_amdgcn_mfma_f32_16x16x32_fp8_fp8(a[m][0], b[n][0], acc[m][n], 0, 0, 0);
    #pragma unroll
    for (int m = 0; m < 4; ++m)
      #pragma unroll
      for (int n = 0; n < 4; ++n)
        acc[m][n] = __builtin_amdgcn_mfma_f32_16x16x32_fp8_fp8(a[m][1], b[n][1], acc[m][n], 0, 0, 0);
    __builtin_amdgcn_s_setprio(0);
  }
}

// ---- FF GEMM (fp8 in, fp8 out K-permuted): C = relu(A@W^T + b)
//      DUAL: C = relu(A@W^T+b) + A2@W2^T + b2

template <int DUAL>
__global__ __launch_bounds__(256) void gemm_ff8(
    const unsigned char* __restrict__ Al, const unsigned char* __restrict__ Wl,
    const float* __restrict__ biasl, unsigned char* __restrict__ Cl,
    const unsigned char* __restrict__ A2l, const unsigned char* __restrict__ W2l,
    const float* __restrict__ bias2l, int nwgL,
    const unsigned char* __restrict__ Ag, const unsigned char* __restrict__ Wg,
    const float* __restrict__ biasg, unsigned char* __restrict__ Cg,
    const unsigned char* __restrict__ A2g, const unsigned char* __restrict__ W2g,
    const float* __restrict__ bias2g) {
  __shared__ unsigned char As[4 * 8192];
  const int tid = threadIdx.x;
  const int lane = tid & 63, wid = tid >> 6;
  const int wr = wid >> 1, wc = wid & 1;

  int tile = xcd_remap(blockIdx.x, gridDim.x);
  const unsigned char *A, *W, *A2, *W2;
  const float *bias, *bias2;
  unsigned char* C;
  if (tile < nwgL) {
    A = Al; W = Wl; bias = biasl; C = Cl; A2 = A2l; W2 = W2l; bias2 = bias2l;
  } else {
    tile -= nwgL;
    A = Ag; W = Wg; bias = biasg; C = Cg; A2 = A2g; W2 = W2g; bias2 = bias2g;
  }
  const long long brow = (long long)(tile >> 2) * 128;
  const long long bcol = (long long)(tile & 3) * 128;

  // A staging: r0 = wave*16 + (lane>>2); phys superslot = tid&3
  const int r0 = (tid >> 6) * 16 + ((tid & 63) >> 2);
  const int csrc = (((tid & 3) ^ ((r0 >> 1) & 3))) * 16;  // key same for r0+64
  const unsigned char* aptr = A + (brow + r0) * DD + csrc;

  const int rA = wr * 64 + (lane & 15);
  const int rBl = wc * 64 + (lane & 15);
  const int qa16 = (lane >> 4) * 16;
  const int offsA = (((lane >> 4) ^ (((lane & 15) >> 1) & 3)) << 4);

  BP4 bp;
  #pragma unroll
  for (int n = 0; n < 4; ++n)
    bp.p[n] = W + (bcol + rBl + n * 16) * DD + qa16;

  f32x4 acc[4][4];
  f32x4 zero = {0.f, 0.f, 0.f, 0.f};
  #pragma unroll
  for (int m = 0; m < 4; ++m)
    #pragma unroll
    for (int n = 0; n < 4; ++n) acc[m][n] = zero;

  gemm_core128_bd(aptr, bp, As, wid, rA, offsA, acc);

  float bv[4];
  #pragma unroll
  for (int n = 0; n < 4; ++n) bv[n] = bias[bcol + wc * 64 + n * 16 + (lane & 15)];

  if constexpr (DUAL) {
    float r[4][4][4];
    #pragma unroll
    for (int m = 0; m < 4; ++m)
      #pragma unroll
      for (int n = 0; n < 4; ++n)
        #pragma unroll
        for (int j = 0; j < 4; ++j)
          r[m][n][j] = fmaxf(acc[m][n][j] + bv[n], 0.f);
    #pragma unroll
    for (int m = 0; m < 4; ++m)
      #pragma unroll
      for (int n = 0; n < 4; ++n) acc[m][n] = zero;

    const unsigned char* aptr2 = A2 + (brow + r0) * DD + csrc;
    BP4 bp2;
    #pragma unroll
    for (int n = 0; n < 4; ++n)
      bp2.p[n] = W2 + (bcol + rBl + n * 16) * DD + qa16;
    gemm_core128_bd(aptr2, bp2, As, wid, rA, offsA, acc);

    float b2[4];
    #pragma unroll
    for (int n = 0; n < 4; ++n) b2[n] = bias2[bcol + wc * 64 + n * 16 + (lane & 15)];

    #pragma unroll
    for (int m = 0; m < 4; ++m) {
      const long long row = brow + wr * 64 + m * 16 + (lane >> 4) * 4;
      #pragma unroll
      for (int j = 0; j < 4; ++j)
        #pragma unroll
        for (int n = 0; n < 4; ++n) {
          const long long col = bcol + wc * 64 + n * 16 + (lane & 15);
          float v = r[m][n][j] + acc[m][n][j] + b2[n];
          C[(row + j) * DD + permute_col(col)] = f2fp8(v);
        }
    }
  } else {
    #pragma unroll
    for (int m = 0; m < 4; ++m) {
      const long long row = brow + wr * 64 + m * 16 + (lane >> 4) * 4;
      #pragma unroll
      for (int j = 0; j < 4; ++j)
        #pragma unroll
        for (int n = 0; n < 4; ++n) {
          const long long col = bcol + wc * 64 + n * 16 + (lane & 15);
          float v = fmaxf(acc[m][n][j] + bv[n], 0.f);
          C[(row + j) * DD + permute_col(col)] = f2fp8(v);
        }
    }
  }
}

// ============================================================================
// jsd: B-direct 128² core + JSD epilogue, no-atomic partials (R13-validated).
// parts[3b+0]=sum_diag(LN2-spn), [3b+1]=sum_all(spn+v), [3b+2]=sum_diag(spn+v)
// ============================================================================

__global__ __launch_bounds__(256) void gemm_jsd128(
    const unsigned char* __restrict__ A, const unsigned char* __restrict__ B,
    const int* __restrict__ batch, float* __restrict__ parts) {
  __shared__ unsigned char As[4 * 8192];
  __shared__ int sbatch[128];
  __shared__ float sred[12];
  const int tid = threadIdx.x;
  const int lane = tid & 63, wid = tid >> 6;
  const int wr = wid >> 1, wc = wid & 1;

  const int tile = xcd_remap(blockIdx.x, gridDim.x);   // 3128 = 391*8
  const long long brow = (long long)(tile >> 3) * 128;
  const long long bcol = (long long)(tile & 7) * 128;

  if (tid < 128) {
    long long gr = brow + tid;
    sbatch[tid] = (gr < N_NODE) ? batch[gr] : -1;   // pad rows never match
  }

  const int r0 = (tid >> 6) * 16 + ((tid & 63) >> 2);
  const int csrc = (((tid & 3) ^ ((r0 >> 1) & 3))) * 16;
  const unsigned char* aptr = A + (brow + r0) * DD + csrc;

  const int rA = wr * 64 + (lane & 15);
  const int rBl = wc * 64 + (lane & 15);
  const int qa16 = (lane >> 4) * 16;
  const int offsA = (((lane >> 4) ^ (((lane & 15) >> 1) & 3)) << 4);

  BP4 bp;
  #pragma unroll
  for (int n = 0; n < 4; ++n)
    bp.p[n] = B + (bcol + rBl + n * 16) * DD + qa16;

  f32x4 acc[4][4];
  f32x4 zero = {0.f, 0.f, 0.f, 0.f};
  #pragma unroll
  for (int m = 0; m < 4; ++m)
    #pragma unroll
    for (int n = 0; n < 4; ++n) acc[m][n] = zero;

  gemm_core128_bd(aptr, bp, As, wid, rA, offsA, acc);

  const float LN2 = 0.69314718055994530942f;
  float sAll = 0.f, sPos = 0.f, sDiag = 0.f;
  #pragma unroll
  for (int m = 0; m < 4; ++m) {
    #pragma unroll
    for (int j = 0; j < 4; ++j) {
      const int lr = wr * 64 + m * 16 + (lane >> 4) * 4 + j;
      const int bg = sbatch[lr];
      #pragma unroll
      for (int n = 0; n < 4; ++n) {
        const int col = (int)bcol + wc * 64 + n * 16 + (lane & 15);
        float v = acc[m][n][j];
        float t = __expf(-fabsf(v));
        float spn = fmaxf(-v, 0.f) + __logf(1.0f + t);   // softplus(-v)
        sAll += spn + v;
        if (col == bg) {
          sPos += LN2 - spn;
          sDiag += spn + v;
        }
      }
    }
  }
  #pragma unroll
  for (int off = 32; off > 0; off >>= 1) {
    sAll  += __shfl_down(sAll, off);
    sPos  += __shfl_down(sPos, off);
    sDiag += __shfl_down(sDiag, off);
  }
  if (lane == 0) { sred[wid] = sPos; sred[4 + wid] = sAll; sred[8 + wid] = sDiag; }
  __syncthreads();
  if (tid == 0) {
    float* o = parts + 3 * blockIdx.x;   // contention-free plain stores
    o[0] = sred[0] + sred[1] + sred[2] + sred[3];
    o[1] = sred[4] + sred[5] + sred[6] + sred[7];
    o[2] = sred[8] + sred[9] + sred[10] + sred[11];
  }
}

// ---- reduce partials (fp64) + finalize, one block ---------------------------

__global__ __launch_bounds__(1024) void reduce_finalize(
    const float* __restrict__ parts, float* __restrict__ out) {
  __shared__ double sp[16], sa[16], sd[16];
  const int tid = threadIdx.x;
  double p = 0.0, a = 0.0, d = 0.0;
  for (int i = tid; i < NJSD; i += 1024) {
    p += (double)parts[3 * i];
    a += (double)parts[3 * i + 1];
    d += (double)parts[3 * i + 2];
  }
  #pragma unroll
  for (int off = 32; off > 0; off >>= 1) {
    p += __shfl_down(p, off);
    a += __shfl_down(a, off);
    d += __shfl_down(d, off);
  }
  const int lane = tid & 63, wid = tid >> 6;
  if (lane == 0) { sp[wid] = p; sa[wid] = a; sd[wid] = d; }
  __syncthreads();
  if (tid == 0) {
    double P = 0.0, Aa = 0.0, Dd = 0.0;
    #pragma unroll
    for (int w = 0; w < 16; ++w) { P += sp[w]; Aa += sa[w]; Dd += sd[w]; }
    const double LN2 = 0.6931471805599453094172321;
    double negSum = (Aa - Dd) - ((double)N_PAD * N_GRAPH - (double)N_NODE) * LN2;
    double Epos = P / (double)N_NODE;
    double Eneg = negSum / ((double)N_NODE * (double)(N_GRAPH - 1));
    out[0] = (float)(Eneg - Epos);
  }
}

// ---- launch -----------------------------------------------------------------

extern "C" void kernel_launch(void* const* d_in, const int* in_sizes, int n_in,
                              void* d_out, int out_size, void* d_ws, size_t ws_size,
                              hipStream_t stream) {
  const float* node  = (const float*)d_in[0];
  const float* graph = (const float*)d_in[1];
  const int*   batch = (const int*)d_in[2];
  const float* lw0 = (const float*)d_in[3];
  const float* lb0 = (const float*)d_in[4];
  const float* lw1 = (const float*)d_in[5];
  const float* lb1 = (const float*)d_in[6];
  const float* lw2 = (const float*)d_in[7];
  const float* lb2 = (const float*)d_in[8];
  const float* lws = (const float*)d_in[9];
  const float* lbs = (const float*)d_in[10];
  const float* gw0 = (const float*)d_in[11];
  const float* gb0 = (const float*)d_in[12];
  const float* gw1 = (const float*)d_in[13];
  const float* gb1 = (const float*)d_in[14];
  const float* gw2 = (const float*)d_in[15];
  const float* gb2 = (const float*)d_in[16];
  const float* gws = (const float*)d_in[17];
  const float* gbs = (const float*)d_in[18];

  // workspace layout (same offsets as R2-R13; fp8 regions)
  char* ws = (char*)d_ws;
  unsigned char* WB8   = (unsigned char*)(ws + 256);          // 8 x 256KB fp8 perm
  float*         parts = (float*)(ws + 2097408LL);            // 3128*3 floats
  unsigned char* XB8   = (unsigned char*)(ws + 4194560LL);    // [N_PAD,512] fp8 perm
  unsigned char* H1_8  = (unsigned char*)(ws + 55443712LL);   // h1; later l_enc
  unsigned char* H2_8  = (unsigned char*)(ws + 106692864LL);
  unsigned char* GXB8  = (unsigned char*)(ws + 157942016LL);
  unsigned char* GH18  = (unsigned char*)(ws + 158990592LL);  // gh1; later g_enc
  unsigned char* GH28  = (unsigned char*)(ws + 160039168LL);
  if (ws_size < 161087744ULL) return;

  WPtrs wp;
  wp.p[0] = lw0; wp.p[1] = lw1; wp.p[2] = lw2; wp.p[3] = lws;
  wp.p[4] = gw0; wp.p[5] = gw1; wp.p[6] = gw2; wp.p[7] = gws;
  cast_w8_kernel<<<1024, 256, 0, stream>>>(wp, WB8);
  cast_pad8_kernel<<<12512, 256, 0, stream>>>(node, XB8, N_NODE, N_PAD);
  cast_pad8_kernel<<<256, 256, 0, stream>>>(graph, GXB8, N_GRAPH, N_GRAPH);

  // ---- ff chain: 128² fp8 B-direct kernels, combined l+g grid ----
  dim3 blk256(256);
  const int nwgL = 4 * 391;
  const int nwgG = 4 * 8;
  dim3 gff(nwgL + nwgG);

  gemm_ff8<0><<<gff, blk256, 0, stream>>>(
      XB8, WB8 + 0 * 262144, lb0, H1_8, nullptr, nullptr, nullptr, nwgL,
      GXB8, WB8 + 4 * 262144, gb0, GH18, nullptr, nullptr, nullptr);
  gemm_ff8<0><<<gff, blk256, 0, stream>>>(
      H1_8, WB8 + 1 * 262144, lb1, H2_8, nullptr, nullptr, nullptr, nwgL,
      GH18, WB8 + 5 * 262144, gb1, GH28, nullptr, nullptr, nullptr);
  // DUAL: reads H2+XB (l) / GH2+GXB (g), writes l_enc/g_enc into H1/GH1
  gemm_ff8<1><<<gff, blk256, 0, stream>>>(
      H2_8, WB8 + 2 * 262144, lb2, H1_8, XB8, WB8 + 3 * 262144, lbs, nwgL,
      GH28, WB8 + 6 * 262144, gb2, GH18, GXB8, WB8 + 7 * 262144, gbs);

  zeropad8_kernel<<<6, 256, 0, stream>>>(H1_8);

  // ---- jsd: 128² fp8 B-direct kernel, partials (no atomics) ----
  dim3 gr(NJSD);                      // 3128 blocks
  gemm_jsd128<<<gr, blk256, 0, stream>>>(H1_8, GH18, batch, parts);
  reduce_finalize<<<1, 1024, 0, stream>>>(parts, (float*)d_out);
}

// Round 16
// 217.121 us; speedup vs baseline: 1.2717x; 1.2717x over previous
//
#include <hip/hip_runtime.h>
#include <hip/hip_bf16.h>

#define N_NODE  50000
#define N_PAD   50048   // 391 * 128  (exactly tiled by 128 -> no guards)
#define N_GRAPH 1024
#define DD      512
#define NK8     8       // fp8 cores: 64-byte K-step, K=512 -> 8 steps
#define NJSD    3128    // jsd grid: 391 * 8

typedef __attribute__((ext_vector_type(4))) float f32x4;
typedef __attribute__((ext_vector_type(2))) long long ll2;

// fp32 -> fp8 e4m3fn, RNE, BRANCHLESS (R8 lesson: early-returns diverge)
__device__ __forceinline__ unsigned char f2fp8(float f) {
  unsigned int u = __builtin_bit_cast(unsigned int, f);
  unsigned int sg = (u >> 24) & 0x80u;
  float a = __builtin_bit_cast(float, u & 0x7fffffffu);
  a = fminf(a, 448.0f);
  unsigned int r = __builtin_bit_cast(unsigned int, a);
  unsigned int rn = r + 0x7ffffu + ((r >> 20) & 1u);   // RNE at mantissa bit 20
  int codeN = (int)(rn >> 20) - (120 << 3);            // ((e+127)<<3|m3) - 960
  int codeS = (int)rintf(a * 512.0f);                  // subnormal grid 2^-9
  int code = (a >= 0.015625f) ? codeN : codeS;
  code = code > 0x7E ? 0x7E : code;
  return (unsigned char)(sg | (unsigned int)code);
}

// K-permutation (R10-verified): within each 64-col group, phys position
// p = ((k>>3)&3)<<4 | (k>>5)<<3 | (k&7). A lane's two MFMA kk-operands are
// then 16 contiguous bytes (one b128 read). Upper bits pass through.
__device__ __forceinline__ long long permute_col(long long c) {
  int o = (int)c & 63;
  int p = (((o >> 3) & 3) << 4) | ((o >> 5) << 3) | (o & 7);
  return (c & ~63LL) | p;
}

__device__ __forceinline__ void gload16(const void* g, void* l) {
  __builtin_amdgcn_global_load_lds(
      (const __attribute__((address_space(1))) unsigned int*)g,
      (__attribute__((address_space(3))) unsigned int*)l, 16, 0, 0);
}

// T1: bijective XCD-chunk remap (m204 variant)
__device__ __forceinline__ int xcd_remap(int bid, int nwg) {
  int xcd = bid & 7;
  int local = bid >> 3;
  int q = nwg >> 3, r = nwg & 7;
  int base = (xcd < r) ? xcd * (q + 1) : r * (q + 1) + (xcd - r) * q;
  return base + local;
}

// ---- fp8 cast kernels (write K-permuted) ------------------------------------

__global__ void cast_pad8_kernel(const float* __restrict__ src,
                                 unsigned char* __restrict__ dst,
                                 int srcRows, int dstRows) {
  long long base = ((long long)blockIdx.x * blockDim.x + threadIdx.x) * 8;
  if (base >= (long long)dstRows * DD) return;
  int row = (int)(base >> 9);
  unsigned long long pk = 0ULL;
  if (row < srcRows) {
    float4 x0 = reinterpret_cast<const float4*>(src + base)[0];
    float4 x1 = reinterpret_cast<const float4*>(src + base)[1];
    pk  = (unsigned long long)f2fp8(x0.x);
    pk |= (unsigned long long)f2fp8(x0.y) << 8;
    pk |= (unsigned long long)f2fp8(x0.z) << 16;
    pk |= (unsigned long long)f2fp8(x0.w) << 24;
    pk |= (unsigned long long)f2fp8(x1.x) << 32;
    pk |= (unsigned long long)f2fp8(x1.y) << 40;
    pk |= (unsigned long long)f2fp8(x1.z) << 48;
    pk |= (unsigned long long)f2fp8(x1.w) << 56;
  }
  *reinterpret_cast<unsigned long long*>(dst + permute_col(base)) = pk;
}

struct WPtrs { const float* p[8]; };

__global__ void cast_w8_kernel(WPtrs ps, unsigned char* __restrict__ dst) {
  long long base = ((long long)blockIdx.x * blockDim.x + threadIdx.x) * 8;
  int mat = (int)(base >> 18);           // 512*512 = 2^18 elems per matrix
  long long off = base & 262143LL;
  const float* s = ps.p[mat] + off;
  float4 x0 = reinterpret_cast<const float4*>(s)[0];
  float4 x1 = reinterpret_cast<const float4*>(s)[1];
  unsigned long long pk;
  pk  = (unsigned long long)f2fp8(x0.x);
  pk |= (unsigned long long)f2fp8(x0.y) << 8;
  pk |= (unsigned long long)f2fp8(x0.z) << 16;
  pk |= (unsigned long long)f2fp8(x0.w) << 24;
  pk |= (unsigned long long)f2fp8(x1.x) << 32;
  pk |= (unsigned long long)f2fp8(x1.y) << 40;
  pk |= (unsigned long long)f2fp8(x1.z) << 48;
  pk |= (unsigned long long)f2fp8(x1.w) << 56;
  *reinterpret_cast<unsigned long long*>(
      dst + (long long)mat * 262144 + permute_col(off)) = pk;
}

__global__ void zeropad8_kernel(unsigned char* __restrict__ H) {
  long long i = (long long)blockIdx.x * blockDim.x + threadIdx.x;
  long long base = (long long)N_NODE * DD + i * 16;
  if (base < (long long)N_PAD * DD) {
    int4 z = {0, 0, 0, 0};
    *reinterpret_cast<int4*>(H + base) = z;
  }
}

// ============================================================================
// 128x128 fp8 core: 3-SLOT circular LDS, depth-2 prefetch, counted vmcnt.
// LDS = 48 KB -> 3 blocks/CU (3 waves/SIMD; R13's 4-slot 64 KB gave only 2).
// Derivation (4 gloads/stage): prologue issues st0,st1 then vmcnt(4) retires
// st0. Step t: issue st_{t+2} (outstanding st_{t+1}+st_{t+2}=8) -> vmcnt(4)
// retires st_{t+1}, needed next step. t=NK-2: vmcnt(0) retires the last stage.
// WAR: st_{t+2} overwrites slot (t-1)%3, whose readers passed this step's
// barrier (their ds_reads completed before reaching it).
// Staging swizzle (R10-verified): phys superslot p=tid&3 of row r holds
// logical p ^ ((r>>1)&3); inverse applied on GLOBAL source (rule 21).
// Read: one ds_read_b128 per fragment at offs=(qa^sa)<<4 (0 conflicts, R10).
// ============================================================================

__device__ __forceinline__ void ff_stage(const unsigned char* aptr,
                                         const unsigned char* bptr, int kbyte,
                                         unsigned char* sA, unsigned char* sB,
                                         int wid) {
  unsigned char* dA = sA + wid * 1024;   // wave-uniform; HW adds lane*16B
  unsigned char* dB = sB + wid * 1024;
  gload16(aptr + kbyte, dA);
  gload16(aptr + 64LL * DD + kbyte, dA + 4096);
  gload16(bptr + kbyte, dB);
  gload16(bptr + 64LL * DD + kbyte, dB + 4096);
}

__device__ __forceinline__ void gemm_core128_fp8(
    const unsigned char* aptr, const unsigned char* bptr,
    unsigned char* As, unsigned char* Bs,
    int wid, int rA, int rB, int offs, f32x4 acc[4][4]) {
  ff_stage(aptr, bptr, 0, As, Bs, wid);
  ff_stage(aptr, bptr, 64, As + 8192, Bs + 8192, wid);
  asm volatile("s_waitcnt vmcnt(4)" ::: "memory");   // st0 retired
  __builtin_amdgcn_sched_barrier(0);
  __builtin_amdgcn_s_barrier();
  #pragma unroll
  for (int t = 0; t < NK8; ++t) {
    if (t) __builtin_amdgcn_s_barrier();
    if (t + 2 < NK8)
      ff_stage(aptr, bptr, (t + 2) * 64, As + ((t + 2) % 3) * 8192,
               Bs + ((t + 2) % 3) * 8192, wid);
    const unsigned char* as = As + (t % 3) * 8192;
    const unsigned char* bs = Bs + (t % 3) * 8192;
    ll2 a[4], b[4];
    #pragma unroll
    for (int m = 0; m < 4; ++m)
      a[m] = *reinterpret_cast<const ll2*>(as + (rA + m * 16) * 64 + offs);
    #pragma unroll
    for (int n = 0; n < 4; ++n)
      b[n] = *reinterpret_cast<const ll2*>(bs + (rB + n * 16) * 64 + offs);
    // end-of-step wait: keep next step's stage landed, never drain mid-loop
    if (t + 2 < NK8)      { asm volatile("s_waitcnt vmcnt(4)" ::: "memory"); }
    else if (t + 2 == NK8){ asm volatile("s_waitcnt vmcnt(0)" ::: "memory"); }
    __builtin_amdgcn_sched_barrier(0);   // rule 18: pin MFMA after waits
    __builtin_amdgcn_s_setprio(1);
    #pragma unroll
    for (int m = 0; m < 4; ++m)
      #pragma unroll
      for (int n = 0; n < 4; ++n)
        acc[m][n] = __builtin_amdgcn_mfma_f32_16x16x32_fp8_fp8(a[m][0], b[n][0], acc[m][n], 0, 0, 0);
    #pragma unroll
    for (int m = 0; m < 4; ++m)
      #pragma unroll
      for (int n = 0; n < 4; ++n)
        acc[m][n] = __builtin_amdgcn_mfma_f32_16x16x32_fp8_fp8(a[m][1], b[n][1], acc[m][n], 0, 0, 0);
    __builtin_amdgcn_s_setprio(0);
  }
}

// ---- FF GEMM (fp8 in, fp8 out K-permuted): C = relu(A@W^T + b)
//      DUAL: C = relu(A@W^T+b) + A2@W2^T + b2

template <int DUAL>
__global__ __launch_bounds__(256, 3) void gemm_ff8(
    const unsigned char* __restrict__ Al, const unsigned char* __restrict__ Wl,
    const float* __restrict__ biasl, unsigned char* __restrict__ Cl,
    const unsigned char* __restrict__ A2l, const unsigned char* __restrict__ W2l,
    const float* __restrict__ bias2l, int nwgL,
    const unsigned char* __restrict__ Ag, const unsigned char* __restrict__ Wg,
    const float* __restrict__ biasg, unsigned char* __restrict__ Cg,
    const unsigned char* __restrict__ A2g, const unsigned char* __restrict__ W2g,
    const float* __restrict__ bias2g) {
  __shared__ unsigned char As[3 * 8192];
  __shared__ unsigned char Bs[3 * 8192];
  const int tid = threadIdx.x;
  const int lane = tid & 63, wid = tid >> 6;
  const int wr = wid >> 1, wc = wid & 1;

  int tile = xcd_remap(blockIdx.x, gridDim.x);
  const unsigned char *A, *W, *A2, *W2;
  const float *bias, *bias2;
  unsigned char* C;
  if (tile < nwgL) {
    A = Al; W = Wl; bias = biasl; C = Cl; A2 = A2l; W2 = W2l; bias2 = bias2l;
  } else {
    tile -= nwgL;
    A = Ag; W = Wg; bias = biasg; C = Cg; A2 = A2g; W2 = W2g; bias2 = bias2g;
  }
  const long long brow = (long long)(tile >> 2) * 128;
  const long long bcol = (long long)(tile & 3) * 128;

  // staging geometry: r0 = wave*16 + (lane>>2); phys superslot = tid&3
  const int r0 = (tid >> 6) * 16 + ((tid & 63) >> 2);
  const int csrc = (((tid & 3) ^ ((r0 >> 1) & 3))) * 16;  // key same for r0+64
  const unsigned char* aptr = A + (brow + r0) * DD + csrc;
  const unsigned char* bptr = W + (bcol + r0) * DD + csrc;

  const int rA = wr * 64 + (lane & 15);
  const int rB = wc * 64 + (lane & 15);
  const int offs = (((lane >> 4) ^ (((lane & 15) >> 1) & 3)) << 4);

  f32x4 acc[4][4];
  f32x4 zero = {0.f, 0.f, 0.f, 0.f};
  #pragma unroll
  for (int m = 0; m < 4; ++m)
    #pragma unroll
    for (int n = 0; n < 4; ++n) acc[m][n] = zero;

  gemm_core128_fp8(aptr, bptr, As, Bs, wid, rA, rB, offs, acc);

  float bv[4];
  #pragma unroll
  for (int n = 0; n < 4; ++n) bv[n] = bias[bcol + wc * 64 + n * 16 + (lane & 15)];

  if constexpr (DUAL) {
    float r[4][4][4];
    #pragma unroll
    for (int m = 0; m < 4; ++m)
      #pragma unroll
      for (int n = 0; n < 4; ++n)
        #pragma unroll
        for (int j = 0; j < 4; ++j)
          r[m][n][j] = fmaxf(acc[m][n][j] + bv[n], 0.f);
    #pragma unroll
    for (int m = 0; m < 4; ++m)
      #pragma unroll
      for (int n = 0; n < 4; ++n) acc[m][n] = zero;

    __builtin_amdgcn_s_barrier();   // protect LDS slot reuse across cores
    const unsigned char* aptr2 = A2 + (brow + r0) * DD + csrc;
    const unsigned char* bptr2 = W2 + (bcol + r0) * DD + csrc;
    gemm_core128_fp8(aptr2, bptr2, As, Bs, wid, rA, rB, offs, acc);

    float b2[4];
    #pragma unroll
    for (int n = 0; n < 4; ++n) b2[n] = bias2[bcol + wc * 64 + n * 16 + (lane & 15)];

    #pragma unroll
    for (int m = 0; m < 4; ++m) {
      const long long row = brow + wr * 64 + m * 16 + (lane >> 4) * 4;
      #pragma unroll
      for (int j = 0; j < 4; ++j)
        #pragma unroll
        for (int n = 0; n < 4; ++n) {
          const long long col = bcol + wc * 64 + n * 16 + (lane & 15);
          float v = r[m][n][j] + acc[m][n][j] + b2[n];
          C[(row + j) * DD + permute_col(col)] = f2fp8(v);
        }
    }
  } else {
    #pragma unroll
    for (int m = 0; m < 4; ++m) {
      const long long row = brow + wr * 64 + m * 16 + (lane >> 4) * 4;
      #pragma unroll
      for (int j = 0; j < 4; ++j)
        #pragma unroll
        for (int n = 0; n < 4; ++n) {
          const long long col = bcol + wc * 64 + n * 16 + (lane & 15);
          float v = fmaxf(acc[m][n][j] + bv[n], 0.f);
          C[(row + j) * DD + permute_col(col)] = f2fp8(v);
        }
    }
  }
}

// ============================================================================
// jsd: 3-slot 128² fp8 core + JSD epilogue, no-atomic partials (R13-validated)
// parts[3b+0]=sum_diag(LN2-spn), [3b+1]=sum_all(spn+v), [3b+2]=sum_diag(spn+v)
// ============================================================================

__global__ __launch_bounds__(256, 3) void gemm_jsd128(
    const unsigned char* __restrict__ A, const unsigned char* __restrict__ B,
    const int* __restrict__ batch, float* __restrict__ parts) {
  __shared__ unsigned char As[3 * 8192];
  __shared__ unsigned char Bs[3 * 8192];
  __shared__ int sbatch[128];
  __shared__ float sred[12];
  const int tid = threadIdx.x;
  const int lane = tid & 63, wid = tid >> 6;
  const int wr = wid >> 1, wc = wid & 1;

  const int tile = xcd_remap(blockIdx.x, gridDim.x);   // 3128 = 391*8
  const long long brow = (long long)(tile >> 3) * 128;
  const long long bcol = (long long)(tile & 7) * 128;

  if (tid < 128) {
    long long gr = brow + tid;
    sbatch[tid] = (gr < N_NODE) ? batch[gr] : -1;   // pad rows never match
  }

  const int r0 = (tid >> 6) * 16 + ((tid & 63) >> 2);
  const int csrc = (((tid & 3) ^ ((r0 >> 1) & 3))) * 16;
  const unsigned char* aptr = A + (brow + r0) * DD + csrc;
  const unsigned char* bptr = B + (bcol + r0) * DD + csrc;

  const int rA = wr * 64 + (lane & 15);
  const int rB = wc * 64 + (lane & 15);
  const int offs = (((lane >> 4) ^ (((lane & 15) >> 1) & 3)) << 4);

  f32x4 acc[4][4];
  f32x4 zero = {0.f, 0.f, 0.f, 0.f};
  #pragma unroll
  for (int m = 0; m < 4; ++m)
    #pragma unroll
    for (int n = 0; n < 4; ++n) acc[m][n] = zero;

  gemm_core128_fp8(aptr, bptr, As, Bs, wid, rA, rB, offs, acc);

  const float LN2 = 0.69314718055994530942f;
  float sAll = 0.f, sPos = 0.f, sDiag = 0.f;
  #pragma unroll
  for (int m = 0; m < 4; ++m) {
    #pragma unroll
    for (int j = 0; j < 4; ++j) {
      const int lr = wr * 64 + m * 16 + (lane >> 4) * 4 + j;
      const int bg = sbatch[lr];
      #pragma unroll
      for (int n = 0; n < 4; ++n) {
        const int col = (int)bcol + wc * 64 + n * 16 + (lane & 15);
        float v = acc[m][n][j];
        float t = __expf(-fabsf(v));
        float spn = fmaxf(-v, 0.f) + __logf(1.0f + t);   // softplus(-v)
        sAll += spn + v;
        if (col == bg) {
          sPos += LN2 - spn;
          sDiag += spn + v;
        }
      }
    }
  }
  #pragma unroll
  for (int off = 32; off > 0; off >>= 1) {
    sAll  += __shfl_down(sAll, off);
    sPos  += __shfl_down(sPos, off);
    sDiag += __shfl_down(sDiag, off);
  }
  if (lane == 0) { sred[wid] = sPos; sred[4 + wid] = sAll; sred[8 + wid] = sDiag; }
  __syncthreads();
  if (tid == 0) {
    float* o = parts + 3 * blockIdx.x;   // contention-free plain stores
    o[0] = sred[0] + sred[1] + sred[2] + sred[3];
    o[1] = sred[4] + sred[5] + sred[6] + sred[7];
    o[2] = sred[8] + sred[9] + sred[10] + sred[11];
  }
}

// ---- reduce partials (fp64) + finalize, one block ---------------------------

__global__ __launch_bounds__(1024) void reduce_finalize(
    const float* __restrict__ parts, float* __restrict__ out) {
  __shared__ double sp[16], sa[16], sd[16];
  const int tid = threadIdx.x;
  double p = 0.0, a = 0.0, d = 0.0;
  for (int i = tid; i < NJSD; i += 1024) {
    p += (double)parts[3 * i];
    a += (double)parts[3 * i + 1];
    d += (double)parts[3 * i + 2];
  }
  #pragma unroll
  for (int off = 32; off > 0; off >>= 1) {
    p += __shfl_down(p, off);
    a += __shfl_down(a, off);
    d += __shfl_down(d, off);
  }
  const int lane = tid & 63, wid = tid >> 6;
  if (lane == 0) { sp[wid] = p; sa[wid] = a; sd[wid] = d; }
  __syncthreads();
  if (tid == 0) {
    double P = 0.0, Aa = 0.0, Dd = 0.0;
    #pragma unroll
    for (int w = 0; w < 16; ++w) { P += sp[w]; Aa += sa[w]; Dd += sd[w]; }
    const double LN2 = 0.6931471805599453094172321;
    double negSum = (Aa - Dd) - ((double)N_PAD * N_GRAPH - (double)N_NODE) * LN2;
    double Epos = P / (double)N_NODE;
    double Eneg = negSum / ((double)N_NODE * (double)(N_GRAPH - 1));
    out[0] = (float)(Eneg - Epos);
  }
}

// ---- launch -----------------------------------------------------------------

extern "C" void kernel_launch(void* const* d_in, const int* in_sizes, int n_in,
                              void* d_out, int out_size, void* d_ws, size_t ws_size,
                              hipStream_t stream) {
  const float* node  = (const float*)d_in[0];
  const float* graph = (const float*)d_in[1];
  const int*   batch = (const int*)d_in[2];
  const float* lw0 = (const float*)d_in[3];
  const float* lb0 = (const float*)d_in[4];
  const float* lw1 = (const float*)d_in[5];
  const float* lb1 = (const float*)d_in[6];
  const float* lw2 = (const float*)d_in[7];
  const float* lb2 = (const float*)d_in[8];
  const float* lws = (const float*)d_in[9];
  const float* lbs = (const float*)d_in[10];
  const float* gw0 = (const float*)d_in[11];
  const float* gb0 = (const float*)d_in[12];
  const float* gw1 = (const float*)d_in[13];
  const float* gb1 = (const float*)d_in[14];
  const float* gw2 = (const float*)d_in[15];
  const float* gb2 = (const float*)d_in[16];
  const float* gws = (const float*)d_in[17];
  const float* gbs = (const float*)d_in[18];

  // workspace layout (same offsets as R2-R14; fp8 regions)
  char* ws = (char*)d_ws;
  unsigned char* WB8   = (unsigned char*)(ws + 256);          // 8 x 256KB fp8 perm
  float*         parts = (float*)(ws + 2097408LL);            // 3128*3 floats
  unsigned char* XB8   = (unsigned char*)(ws + 4194560LL);    // [N_PAD,512] fp8 perm
  unsigned char* H1_8  = (unsigned char*)(ws + 55443712LL);   // h1; later l_enc
  unsigned char* H2_8  = (unsigned char*)(ws + 106692864LL);
  unsigned char* GXB8  = (unsigned char*)(ws + 157942016LL);
  unsigned char* GH18  = (unsigned char*)(ws + 158990592LL);  // gh1; later g_enc
  unsigned char* GH28  = (unsigned char*)(ws + 160039168LL);
  if (ws_size < 161087744ULL) return;

  WPtrs wp;
  wp.p[0] = lw0; wp.p[1] = lw1; wp.p[2] = lw2; wp.p[3] = lws;
  wp.p[4] = gw0; wp.p[5] = gw1; wp.p[6] = gw2; wp.p[7] = gws;
  cast_w8_kernel<<<1024, 256, 0, stream>>>(wp, WB8);
  cast_pad8_kernel<<<12512, 256, 0, stream>>>(node, XB8, N_NODE, N_PAD);
  cast_pad8_kernel<<<256, 256, 0, stream>>>(graph, GXB8, N_GRAPH, N_GRAPH);

  // ---- ff chain: 128² fp8 3-slot counted-vmcnt kernels, combined l+g grid ----
  dim3 blk256(256);
  const int nwgL = 4 * 391;
  const int nwgG = 4 * 8;
  dim3 gff(nwgL + nwgG);

  gemm_ff8<0><<<gff, blk256, 0, stream>>>(
      XB8, WB8 + 0 * 262144, lb0, H1_8, nullptr, nullptr, nullptr, nwgL,
      GXB8, WB8 + 4 * 262144, gb0, GH18, nullptr, nullptr, nullptr);
  gemm_ff8<0><<<gff, blk256, 0, stream>>>(
      H1_8, WB8 + 1 * 262144, lb1, H2_8, nullptr, nullptr, nullptr, nwgL,
      GH18, WB8 + 5 * 262144, gb1, GH28, nullptr, nullptr, nullptr);
  // DUAL: reads H2+XB (l) / GH2+GXB (g), writes l_enc/g_enc into H1/GH1
  gemm_ff8<1><<<gff, blk256, 0, stream>>>(
      H2_8, WB8 + 2 * 262144, lb2, H1_8, XB8, WB8 + 3 * 262144, lbs, nwgL,
      GH28, WB8 + 6 * 262144, gb2, GH18, GXB8, WB8 + 7 * 262144, gbs);

  zeropad8_kernel<<<6, 256, 0, stream>>>(H1_8);

  // ---- jsd: 128² fp8 3-slot kernel, partials (no atomics) ----
  dim3 gr(NJSD);                      // 3128 blocks
  gemm_jsd128<<<gr, blk256, 0, stream>>>(H1_8, GH18, batch, parts);
  reduce_finalize<<<1, 1024, 0, stream>>>(parts, (float*)d_out);
}